// Round 1
// baseline (493.058 us; speedup 1.0000x reference)
//
#include <hip/hip_runtime.h>

// Persistent fused RNN: one 64-thread block (1 wave) owns 16 batch rows for all
// 128 timesteps. pre^T[j][m] = sum_k Wcomb[k][j] * IN[m][k], IN = [h(100);x(28)],
// K=128 = 4 slices of mfma_f32_16x16x32_bf16. A = W^T held in 112 VGPRs,
// B-frags = ds_read_b128 from 272B-stride LDS rows (bank-balanced), h state
// double-buffered in LDS as bf16, accumulate fp32, tanh in fp32.

#define SEQ   128
#define BATCH 16384
#define NIN   28
#define NHID  100
#define NCLS  10

#define HSTR  136   // bf16 elements per LDS row: 128 used + 8 pad -> 272B (16B aligned)
#define WROWS 112   // j rows (100 used, 12 zero-pad)

typedef __bf16 bf16x8 __attribute__((ext_vector_type(8)));
typedef float  f32x4  __attribute__((ext_vector_type(4)));

__device__ __forceinline__ unsigned short f2bf(float f) {
    unsigned u = __builtin_bit_cast(unsigned, f);
    u += 0x7FFFu + ((u >> 16) & 1u);          // RNE
    return (unsigned short)(u >> 16);
}
__device__ __forceinline__ float bf2f(unsigned short b) {
    unsigned u = ((unsigned)b) << 16;
    return __builtin_bit_cast(float, u);
}
__device__ __forceinline__ float tanh_fast(float x) {
    // tanh(x) = 1 - 2/(e^{2x}+1); robust at +-inf (rcp(inf)=0 -> 1, exp(-big)=0 -> -1)
    float t = __expf(2.0f * x);
    float r = __builtin_amdgcn_rcpf(t + 1.0f);
    return __builtin_fmaf(-2.0f, r, 1.0f);
}

__global__ __launch_bounds__(64, 1) void rnn_fused_kernel(
    const float* __restrict__ data, const float* __restrict__ w_xh,
    const float* __restrict__ b_xh, const float* __restrict__ w_hh,
    const float* __restrict__ b_hh, const float* __restrict__ w_fc,
    const float* __restrict__ b_fc, float* __restrict__ out)
{
    __shared__ unsigned short WT[WROWS * HSTR];   // W^T[j][k] bf16 (k<100: w_hh, 100..127: w_xh)
    __shared__ unsigned short hb[2 * 16 * HSTR];  // double-buffered IN rows: [h(100) | pad | x(28) @100..127]

    const int tid = threadIdx.x;   // 0..63
    const int x   = tid & 15;      // row-in-tile (m) for B/D-col; j-low for A
    const int g   = tid >> 4;      // lane group
    const int m0  = blockIdx.x * 16;

    // ---- prologue: build W^T in LDS (coalesced global reads over j) ----
    for (int idx = tid; idx < WROWS * HSTR; idx += 64) {
        int j = idx % WROWS;
        int k = idx / WROWS;
        float v = 0.0f;
        if (j < NHID) {
            if (k < NHID)            v = w_hh[k * NHID + j];
            else if (k < NHID + NIN) v = w_xh[(k - NHID) * NHID + j];
        }
        WT[j * HSTR + k] = f2bf(v);
    }
    // zero both h buffers (h0 = 0; also clears pad region)
    {
        unsigned int* hb32 = (unsigned int*)hb;
        for (int idx = tid; idx < (2 * 16 * HSTR) / 2; idx += 64) hb32[idx] = 0u;
    }
    // stage x(t=0) into buffer 0
    {
        const float* src = data + (size_t)m0 * NIN;
        #pragma unroll
        for (int rep = 0; rep < 7; ++rep) {
            int idx = rep * 64 + tid;           // 448 = 16*28 elements exactly
            int m = idx / NIN, i = idx - m * NIN;
            hb[m * HSTR + NHID + i] = f2bf(src[idx]);
        }
    }
    // bias fragments: b_xh + b_hh at j = 16*jt + 4*g + r (clamped for pad rows)
    f32x4 biasf[7];
    #pragma unroll
    for (int jt = 0; jt < 7; ++jt)
        #pragma unroll
        for (int r = 0; r < 4; ++r) {
            int j  = jt * 16 + g * 4 + r;
            int jc = (j < NHID) ? j : (NHID - 1);
            biasf[jt][r] = b_xh[jc] + b_hh[jc];
        }
    __syncthreads();

    // A fragments: lane holds W^T[j = 16jt + x][k = 32kt + 8g .. +7]  (112 VGPRs)
    bf16x8 aw[7][4];
    #pragma unroll
    for (int jt = 0; jt < 7; ++jt)
        #pragma unroll
        for (int kt = 0; kt < 4; ++kt)
            aw[jt][kt] = *(const bf16x8*)&WT[(jt * 16 + x) * HSTR + kt * 32 + g * 8];

    // ---- 128 sequential steps ----
    for (int t = 0; t < SEQ; ++t) {
        unsigned short* cur = hb + (t & 1) * (16 * HSTR);
        unsigned short* nxt = hb + ((t & 1) ^ 1) * (16 * HSTR);

        // prefetch x(t+1) early — consumed at end of step, HBM latency hidden
        int t1 = (t < SEQ - 1) ? t + 1 : SEQ - 1;
        const float* src = data + ((size_t)t1 * BATCH + m0) * NIN;
        float xv[7];
        #pragma unroll
        for (int rep = 0; rep < 7; ++rep) xv[rep] = src[rep * 64 + tid];

        // B fragments: lane holds IN[m = x][k = 32kt + 8g .. +7]
        bf16x8 bq[4];
        #pragma unroll
        for (int kt = 0; kt < 4; ++kt)
            bq[kt] = *(const bf16x8*)&cur[x * HSTR + kt * 32 + g * 8];

        f32x4 acc[7];
        #pragma unroll
        for (int jt = 0; jt < 7; ++jt) acc[jt] = biasf[jt];
        #pragma unroll
        for (int kt = 0; kt < 4; ++kt)
            #pragma unroll
            for (int jt = 0; jt < 7; ++jt)
                acc[jt] = __builtin_amdgcn_mfma_f32_16x16x32_bf16(aw[jt][kt], bq[kt], acc[jt], 0, 0, 0);

        // tanh + write h(t+1): lane owns 4 consecutive j = 16jt + 4g + r, row m = x
        #pragma unroll
        for (int jt = 0; jt < 7; ++jt) {
            int j0 = jt * 16 + g * 4;
            if (j0 < NHID) {   // static for jt<6; masks g>0 in tile 6 (j>=100 = x region!)
                unsigned short h0 = f2bf(tanh_fast(acc[jt][0]));
                unsigned short h1 = f2bf(tanh_fast(acc[jt][1]));
                unsigned short h2 = f2bf(tanh_fast(acc[jt][2]));
                unsigned short h3 = f2bf(tanh_fast(acc[jt][3]));
                unsigned int lo = (unsigned)h0 | ((unsigned)h1 << 16);
                unsigned int hi = (unsigned)h2 | ((unsigned)h3 << 16);
                *(unsigned int*)&nxt[x * HSTR + j0]     = lo;
                *(unsigned int*)&nxt[x * HSTR + j0 + 2] = hi;
            }
        }
        // write x(t+1)
        #pragma unroll
        for (int rep = 0; rep < 7; ++rep) {
            int idx = rep * 64 + tid;
            int m = idx / NIN, i = idx - m * NIN;
            nxt[m * HSTR + NHID + i] = f2bf(xv[rep]);
        }
        __syncthreads();   // single wave: cheap; enforces LDS ordering across steps
    }

    // ---- tail: out[m][c] = b_fc[c] + sum_j h_T[m][j] * w_fc[j][c] ----
    // final h (bf16) is in buffer 0 after 128 steps
    for (int o = tid; o < 16 * NCLS; o += 64) {
        int m = o / NCLS, c = o - (o / NCLS) * NCLS;
        float s = b_fc[c];
        for (int j = 0; j < NHID; ++j)
            s = __builtin_fmaf(bf2f(hb[m * HSTR + j]), w_fc[j * NCLS + c], s);
        out[(size_t)(m0 + m) * NCLS + c] = s;
    }
}

extern "C" void kernel_launch(void* const* d_in, const int* in_sizes, int n_in,
                              void* d_out, int out_size, void* d_ws, size_t ws_size,
                              hipStream_t stream) {
    const float* data = (const float*)d_in[0];
    const float* w_xh = (const float*)d_in[1];
    const float* b_xh = (const float*)d_in[2];
    const float* w_hh = (const float*)d_in[3];
    const float* b_hh = (const float*)d_in[4];
    const float* w_fc = (const float*)d_in[5];
    const float* b_fc = (const float*)d_in[6];
    float* outp = (float*)d_out;
    (void)in_sizes; (void)n_in; (void)out_size; (void)d_ws; (void)ws_size;
    rnn_fused_kernel<<<dim3(BATCH / 16), dim3(64), 0, stream>>>(
        data, w_xh, b_xh, w_hh, b_hh, w_fc, b_fc, outp);
}

// Round 5
// 382.980 us; speedup vs baseline: 1.2874x; 1.2874x over previous
//
#include <hip/hip_runtime.h>

// Fused persistent RNN, round 2: 256-thread blocks (4 waves) own 16 batch rows.
// j-split: wave w finalizes output tiles jt={2w,2w+1} (wave3: jt6 + x staging).
// All waves read the same B-fragments (shared LDS h rows); one barrier/step.
// W^T staging LDS aliases the h double-buffer (transient) -> 30.5KB/block.
// 4096 waves total = 4 waves/SIMD (vs 1 before).

#define SEQ   128
#define BATCH 16384
#define NIN   28
#define NHID  100
#define NCLS  10

#define HSTR  136   // bf16 elems per LDS row: 100 h | 28 x | 8 pad = 272B
#define WROWS 112   // padded j rows for W^T

typedef __bf16 bf16x8 __attribute__((ext_vector_type(8)));
typedef float  f32x4  __attribute__((ext_vector_type(4)));

__device__ __forceinline__ unsigned short f2bf(float f) {
    unsigned u = __builtin_bit_cast(unsigned, f);
    u += 0x7FFFu + ((u >> 16) & 1u);          // RNE
    return (unsigned short)(u >> 16);
}
__device__ __forceinline__ float bf2f(unsigned short b) {
    unsigned u = ((unsigned)b) << 16;
    return __builtin_bit_cast(float, u);
}
__device__ __forceinline__ float tanh_fast(float x) {
    // tanh(x) = 1 - 2/(e^{2x}+1); robust at +-inf
    float t = __expf(2.0f * x);
    float r = __builtin_amdgcn_rcpf(t + 1.0f);
    return __builtin_fmaf(-2.0f, r, 1.0f);
}
__device__ __forceinline__ unsigned cvt_pk_bf16(float lo, float hi) {
    unsigned d;
    asm("v_cvt_pk_bf16_f32 %0, %1, %2" : "=v"(d) : "v"(lo), "v"(hi));
    return d;   // bf16(lo) in [15:0], bf16(hi) in [31:16] -> little-endian pair
}

__global__ __launch_bounds__(256, 4) void rnn_fused_kernel(
    const float* __restrict__ data, const float* __restrict__ w_xh,
    const float* __restrict__ b_xh, const float* __restrict__ w_hh,
    const float* __restrict__ b_hh, const float* __restrict__ w_fc,
    const float* __restrict__ b_fc, float* __restrict__ out)
{
    // One pool: W^T (30464B, transient) overlaps h double-buffer (8704B, steady)
    __shared__ unsigned short pool[WROWS * HSTR];
    unsigned short* WT = pool;
    unsigned short* hb = pool;

    const int tid  = threadIdx.x;    // 0..255
    const int wid  = tid >> 6;       // wave 0..3
    const int lane = tid & 63;
    const int x    = lane & 15;      // MFMA row-in-tile (m) for B/D-col; j-low for A
    const int g    = lane >> 4;      // lane group 0..3
    const int m0   = blockIdx.x * 16;

    const int JT0 = wid * 2;                 // owned j-tiles: JT0, JT0+1
    const int NT  = (wid < 3) ? 2 : 1;       // wave3 owns only jt6

    // ---- prologue: build W^T[j][k] bf16 in LDS (k<100: w_hh, 100..127: w_xh) ----
    for (int idx = tid; idx < WROWS * HSTR; idx += 256) {
        int j = idx % WROWS;
        int k = idx / WROWS;
        float v = 0.0f;
        if (j < NHID) {
            if (k < NHID)            v = w_hh[k * NHID + j];
            else if (k < NHID + NIN) v = w_xh[(k - NHID) * NHID + j];
        }
        WT[j * HSTR + k] = f2bf(v);
    }
    __syncthreads();

    // A fragments for owned tiles: W^T[j = 16(JT0+jl) + x][k = 32kt + 8g .. +7]
    bf16x8 aw[2][4];
    #pragma unroll
    for (int jl = 0; jl < 2; ++jl)
        if (jl < NT)
            #pragma unroll
            for (int kt = 0; kt < 4; ++kt)
                aw[jl][kt] = *(const bf16x8*)&WT[((JT0 + jl) * 16 + x) * HSTR + kt * 32 + g * 8];

    // bias fragments for owned tiles (clamped for pad rows j>=100)
    f32x4 biasf[2];
    #pragma unroll
    for (int jl = 0; jl < 2; ++jl)
        #pragma unroll
        for (int r = 0; r < 4; ++r) {
            int j  = (JT0 + jl) * 16 + g * 4 + r;
            int jc = (j < NHID) ? j : (NHID - 1);
            biasf[jl][r] = b_xh[jc] + b_hh[jc];
        }
    __syncthreads();   // all WT reads drained before pool is reused as hb

    // zero h-buffer 0 (h0 = 0; buffer 1 is fully overwritten each step)
    {
        unsigned int* hb32 = (unsigned int*)hb;
        for (int idx = tid; idx < (16 * HSTR) / 2; idx += 256) hb32[idx] = 0u;
    }
    __syncthreads();
    // stage x(t=0) into buffer 0: 224 float2 pairs (28 even -> pairs never straddle rows)
    if (tid < 224) {
        float2 v = *(const float2*)(data + (size_t)m0 * NIN + 2 * tid);
        int m = tid / 14, i2 = 2 * (tid - m * 14);
        *(unsigned int*)&hb[m * HSTR + NHID + i2] = cvt_pk_bf16(v.x, v.y);
    }
    __syncthreads();

    // ---- 128 sequential steps ----
    for (int t = 0; t < SEQ; ++t) {
        unsigned short* cur = hb + (t & 1) * (16 * HSTR);
        unsigned short* nxt = hb + ((t & 1) ^ 1) * (16 * HSTR);

        // wave3 prefetches x(t+1) early; consumed at end of step
        float2 xv[4];
        if (wid == 3) {
            int t1 = (t < SEQ - 1) ? t + 1 : t;
            const float* src = data + ((size_t)t1 * BATCH + m0) * NIN;
            #pragma unroll
            for (int r = 0; r < 4; ++r) {
                int idx = r * 64 + lane;
                if (idx < 224) xv[r] = *(const float2*)(src + 2 * idx);
            }
        }

        // B fragments (all waves, same addresses): IN[m = x][k = 32kt + 8g .. +7]
        bf16x8 bq[4];
        #pragma unroll
        for (int kt = 0; kt < 4; ++kt)
            bq[kt] = *(const bf16x8*)&cur[x * HSTR + kt * 32 + g * 8];

        f32x4 acc[2];
        acc[0] = biasf[0];
        acc[1] = biasf[1];
        #pragma unroll
        for (int kt = 0; kt < 4; ++kt) {
            acc[0] = __builtin_amdgcn_mfma_f32_16x16x32_bf16(aw[0][kt], bq[kt], acc[0], 0, 0, 0);
            if (NT > 1)   // wave-uniform
                acc[1] = __builtin_amdgcn_mfma_f32_16x16x32_bf16(aw[1][kt], bq[kt], acc[1], 0, 0, 0);
        }

        // tanh + pack + write owned h tiles: lane owns j = 16(JT0+jl) + 4g .. +3, row m = x
        #pragma unroll
        for (int jl = 0; jl < 2; ++jl) {
            if (jl < NT) {
                int j0 = (JT0 + jl) * 16 + 4 * g;
                float t0 = tanh_fast(acc[jl][0]);
                float t1 = tanh_fast(acc[jl][1]);
                float t2 = tanh_fast(acc[jl][2]);
                float t3 = tanh_fast(acc[jl][3]);
                if (j0 < NHID) {   // masks g>0 in tile 6 (j>=100 = x region)
                    unsigned lo = cvt_pk_bf16(t0, t1);
                    unsigned hi = cvt_pk_bf16(t2, t3);
                    unsigned long long q = ((unsigned long long)hi << 32) | (unsigned long long)lo;
                    *(unsigned long long*)&nxt[x * HSTR + j0] = q;  // j0%4==0 -> 8B aligned
                }
            }
        }
        // wave3 writes x(t+1)
        if (wid == 3) {
            #pragma unroll
            for (int r = 0; r < 4; ++r) {
                int idx = r * 64 + lane;
                if (idx < 224) {
                    int m = idx / 14, i2 = 2 * (idx - m * 14);
                    *(unsigned int*)&nxt[m * HSTR + NHID + i2] = cvt_pk_bf16(xv[r].x, xv[r].y);
                }
            }
        }
        __syncthreads();
    }

    // ---- tail: out[m][c] = b_fc[c] + sum_j h_T[m][j] * w_fc[j][c] ----
    // after 128 steps the final h is in buffer 0
    for (int o = tid; o < 16 * NCLS; o += 256) {
        int m = o / NCLS, c = o - (o / NCLS) * NCLS;
        float s = b_fc[c];
        for (int j = 0; j < NHID; ++j)
            s = __builtin_fmaf(bf2f(hb[m * HSTR + j]), w_fc[j * NCLS + c], s);
        out[(size_t)(m0 + m) * NCLS + c] = s;
    }
}

extern "C" void kernel_launch(void* const* d_in, const int* in_sizes, int n_in,
                              void* d_out, int out_size, void* d_ws, size_t ws_size,
                              hipStream_t stream) {
    const float* data = (const float*)d_in[0];
    const float* w_xh = (const float*)d_in[1];
    const float* b_xh = (const float*)d_in[2];
    const float* w_hh = (const float*)d_in[3];
    const float* b_hh = (const float*)d_in[4];
    const float* w_fc = (const float*)d_in[5];
    const float* b_fc = (const float*)d_in[6];
    float* outp = (float*)d_out;
    (void)in_sizes; (void)n_in; (void)out_size; (void)d_ws; (void)ws_size;
    rnn_fused_kernel<<<dim3(BATCH / 16), dim3(256), 0, stream>>>(
        data, w_xh, b_xh, w_hh, b_hh, w_fc, b_fc, outp);
}

// Round 6
// 376.802 us; speedup vs baseline: 1.3085x; 1.0164x over previous
//
#include <hip/hip_runtime.h>

// Fused persistent RNN, round 3: 512-thread blocks (8 waves) own 16 batch rows.
// Wave w (w<7) finalizes j-tile w only: 4 MFMA + 4 tanh + one 8B LDS write.
// Wave 7 is a dedicated x(t+1) stager (prefetch fully off compute waves' path).
// 1024 blocks x 8 waves = 8192 waves = 8 waves/SIMD (hardware max occupancy).
// LDS pool 30.5KB (W^T staging aliases h double-buffer) -> 4 blocks/CU = 32 w/CU.

#define SEQ   128
#define BATCH 16384
#define NIN   28
#define NHID  100
#define NCLS  10

#define HSTR  136   // bf16 elems per LDS row: 100 h | 28 x | 8 pad = 272B (16B-aligned)
#define WROWS 112   // padded j rows for W^T

typedef __bf16 bf16x8 __attribute__((ext_vector_type(8)));
typedef float  f32x4  __attribute__((ext_vector_type(4)));

__device__ __forceinline__ unsigned short f2bf(float f) {
    unsigned u = __builtin_bit_cast(unsigned, f);
    u += 0x7FFFu + ((u >> 16) & 1u);          // RNE
    return (unsigned short)(u >> 16);
}
__device__ __forceinline__ float bf2f(unsigned short b) {
    unsigned u = ((unsigned)b) << 16;
    return __builtin_bit_cast(float, u);
}
__device__ __forceinline__ float tanh_fast(float x) {
    // tanh(x) = 1 - 2/(e^{2x}+1); robust at +-inf
    float t = __expf(2.0f * x);
    float r = __builtin_amdgcn_rcpf(t + 1.0f);
    return __builtin_fmaf(-2.0f, r, 1.0f);
}
__device__ __forceinline__ unsigned cvt_pk_bf16(float lo, float hi) {
    unsigned d;
    asm("v_cvt_pk_bf16_f32 %0, %1, %2" : "=v"(d) : "v"(lo), "v"(hi));
    return d;   // bf16(lo) in [15:0], bf16(hi) in [31:16]
}

__global__ __launch_bounds__(512, 8) void rnn_fused_kernel(
    const float* __restrict__ data, const float* __restrict__ w_xh,
    const float* __restrict__ b_xh, const float* __restrict__ w_hh,
    const float* __restrict__ b_hh, const float* __restrict__ w_fc,
    const float* __restrict__ b_fc, float* __restrict__ out)
{
    // One pool: W^T (30464B, transient) overlaps h double-buffer (8704B, steady)
    __shared__ unsigned short pool[WROWS * HSTR];
    unsigned short* WT = pool;
    unsigned short* hb = pool;

    const int tid  = threadIdx.x;    // 0..511
    const int wid  = tid >> 6;       // wave 0..7
    const int lane = tid & 63;
    const int x    = lane & 15;      // MFMA row-in-tile (m) for B/D-col; j-low for A
    const int g    = lane >> 4;      // lane group 0..3
    const int m0   = blockIdx.x * 16;

    const bool compute = (wid < 7);  // waves 0..6 own j-tile wid; wave 7 stages x

    // ---- prologue: build W^T[j][k] bf16 in LDS (k<100: w_hh, 100..127: w_xh) ----
    for (int idx = tid; idx < WROWS * HSTR; idx += 512) {
        int j = idx % WROWS;
        int k = idx / WROWS;
        float v = 0.0f;
        if (j < NHID) {
            if (k < NHID)            v = w_hh[k * NHID + j];
            else if (k < NHID + NIN) v = w_xh[(k - NHID) * NHID + j];
        }
        WT[j * HSTR + k] = f2bf(v);
    }
    __syncthreads();

    // A fragments: W^T[j = 16*wid + x][k = 32kt + 8g .. +7]
    bf16x8 aw[4];
    f32x4  biasf = {0.f, 0.f, 0.f, 0.f};
    if (compute) {
        #pragma unroll
        for (int kt = 0; kt < 4; ++kt)
            aw[kt] = *(const bf16x8*)&WT[(wid * 16 + x) * HSTR + kt * 32 + g * 8];
        #pragma unroll
        for (int r = 0; r < 4; ++r) {
            int j  = wid * 16 + g * 4 + r;
            int jc = (j < NHID) ? j : (NHID - 1);
            biasf[r] = b_xh[jc] + b_hh[jc];
        }
    }
    __syncthreads();   // all WT reads drained before pool is reused as hb

    // zero h-buffer 0 (h0 = 0; buffer 1 fully overwritten each step)
    {
        unsigned int* hb32 = (unsigned int*)hb;
        for (int idx = tid; idx < (16 * HSTR) / 2; idx += 512) hb32[idx] = 0u;
    }
    __syncthreads();
    // stage x(t=0) into buffer 0: 224 float2 pairs (rows have even length 28)
    if (tid < 224) {
        float2 v = *(const float2*)(data + (size_t)m0 * NIN + 2 * tid);
        int m = tid / 14, i2 = 2 * (tid - m * 14);
        *(unsigned int*)&hb[m * HSTR + NHID + i2] = cvt_pk_bf16(v.x, v.y);
    }
    __syncthreads();

    // ---- 128 sequential steps ----
    for (int t = 0; t < SEQ; ++t) {
        unsigned short* cur = hb + (t & 1) * (16 * HSTR);
        unsigned short* nxt = hb + ((t & 1) ^ 1) * (16 * HSTR);

        if (compute) {
            // B fragments: IN[m = x][k = 32kt + 8g .. +7]
            bf16x8 bq[4];
            #pragma unroll
            for (int kt = 0; kt < 4; ++kt)
                bq[kt] = *(const bf16x8*)&cur[x * HSTR + kt * 32 + g * 8];

            f32x4 acc = biasf;
            #pragma unroll
            for (int kt = 0; kt < 4; ++kt)
                acc = __builtin_amdgcn_mfma_f32_16x16x32_bf16(aw[kt], bq[kt], acc, 0, 0, 0);

            // tanh + pack + write owned tile: lane owns j = 16*wid + 4g .. +3, row m = x
            float t0 = tanh_fast(acc[0]);
            float t1 = tanh_fast(acc[1]);
            float t2 = tanh_fast(acc[2]);
            float t3 = tanh_fast(acc[3]);
            int j0 = wid * 16 + 4 * g;
            if (j0 < NHID) {   // masks g>0 in tile 6 (j>=100 = x region)
                unsigned lo = cvt_pk_bf16(t0, t1);
                unsigned hi = cvt_pk_bf16(t2, t3);
                unsigned long long q = ((unsigned long long)hi << 32) | (unsigned long long)lo;
                *(unsigned long long*)&nxt[x * HSTR + j0] = q;  // 8B aligned
            }
        } else {
            // wave 7: prefetch + write x(t+1)
            int t1s = (t < SEQ - 1) ? t + 1 : t;
            const float* src = data + ((size_t)t1s * BATCH + m0) * NIN;
            float2 xv[4];
            #pragma unroll
            for (int r = 0; r < 4; ++r) {
                int idx = r * 64 + lane;
                if (idx < 224) xv[r] = *(const float2*)(src + 2 * idx);
            }
            #pragma unroll
            for (int r = 0; r < 4; ++r) {
                int idx = r * 64 + lane;
                if (idx < 224) {
                    int m = idx / 14, i2 = 2 * (idx - m * 14);
                    *(unsigned int*)&nxt[m * HSTR + NHID + i2] = cvt_pk_bf16(xv[r].x, xv[r].y);
                }
            }
        }
        __syncthreads();
    }

    // ---- tail: out[m][c] = b_fc[c] + sum_j h_T[m][j] * w_fc[j][c] ----
    // after 128 steps the final h is in buffer 0
    for (int o = tid; o < 16 * NCLS; o += 512) {
        int m = o / NCLS, c = o - (o / NCLS) * NCLS;
        float s = b_fc[c];
        for (int j = 0; j < NHID; ++j)
            s = __builtin_fmaf(bf2f(hb[m * HSTR + j]), w_fc[j * NCLS + c], s);
        out[(size_t)(m0 + m) * NCLS + c] = s;
    }
}

extern "C" void kernel_launch(void* const* d_in, const int* in_sizes, int n_in,
                              void* d_out, int out_size, void* d_ws, size_t ws_size,
                              hipStream_t stream) {
    const float* data = (const float*)d_in[0];
    const float* w_xh = (const float*)d_in[1];
    const float* b_xh = (const float*)d_in[2];
    const float* w_hh = (const float*)d_in[3];
    const float* b_hh = (const float*)d_in[4];
    const float* w_fc = (const float*)d_in[5];
    const float* b_fc = (const float*)d_in[6];
    float* outp = (float*)d_out;
    (void)in_sizes; (void)n_in; (void)out_size; (void)d_ws; (void)ws_size;
    rnn_fused_kernel<<<dim3(BATCH / 16), dim3(512), 0, stream>>>(
        data, w_xh, b_xh, w_hh, b_hh, w_fc, b_fc, outp);
}